// Round 6
// baseline (117.487 us; speedup 1.0000x reference)
//
#include <hip/hip_runtime.h>

#define TT 2048
#define EMB 1024
#define NH 16
#define HD 64
#define CTX 250

typedef __attribute__((ext_vector_type(4))) float f32x4;
typedef __attribute__((ext_vector_type(8))) short s16x8;
typedef __attribute__((ext_vector_type(4))) short s16x4;

#define LDS_PTR(p) ((__attribute__((address_space(3))) void*)(p))
#define GLB_PTR(p) ((const __attribute__((address_space(1))) void*)(p))

__device__ __forceinline__ short f2bf(float f) {
  union { float f; unsigned u; } v; v.f = f;
  unsigned r = v.u + 0x7fffu + ((v.u >> 16) & 1u);
  return (short)(r >> 16);
}
__device__ __forceinline__ float bf2f(unsigned short u) {
  union { unsigned u; float f; } v; v.u = ((unsigned)u) << 16;
  return v.f;
}

// one kernel converts all three f32 inputs to bf16
// segments (float4 units): q = 1048576, wi = 786432, wo = 262144; total 2097152
__global__ void cvt_all(const float* __restrict__ q, const float* __restrict__ wi,
                        const float* __restrict__ wo, short* __restrict__ qo,
                        short* __restrict__ wio, short* __restrict__ woo) {
  int i = blockIdx.x * blockDim.x + threadIdx.x;
  const float* src; short* dst; int off;
  if (i < 1048576)      { src = q;  dst = qo;  off = i; }
  else if (i < 1835008) { src = wi; dst = wio; off = i - 1048576; }
  else                  { src = wo; dst = woo; off = i - 1835008; }
  float4 v = reinterpret_cast<const float4*>(src)[off];
  s16x4 o; o[0] = f2bf(v.x); o[1] = f2bf(v.y); o[2] = f2bf(v.z); o[3] = f2bf(v.w);
  *reinterpret_cast<s16x4*>(dst + off * 4) = o;
}

// ---------------------------------------------------------------------------
// Pipelined 256x256 GEMM, BK=32, 8 waves (2M x 4N), double-buffered LDS.
// C[M][N] = A[M][K] * W[N][K]^T, bf16 in, MFMA 16x16x32.
// LDS holds MFMA subtiles in FRAGMENT-MAJOR order (16 rows x 32 k = 1KB each):
// staging pre-gathers fragment order from global (per-lane src), every ds_read
// is base + lane*16 -> coalesced, conflict-free.
// Pipeline: stage tile t+1 at start of tile t; vmcnt drains a full tile later.
// ---------------------------------------------------------------------------
template<bool BF16OUT>
__global__ __launch_bounds__(512, 2) void gemm_256(const short* __restrict__ A,
                                                   const short* __restrict__ W,
                                                   void* __restrict__ Cv, int N, int K) {
  __shared__ __align__(16) short ldsbuf[2][2][8192];  // [dbuf][A/B][16 subtiles x 512]
  const int tid = threadIdx.x;
  const int lane = tid & 63;
  const int wid = tid >> 6;
  const int lr = lane & 15, lg = lane >> 4;
  const int wm = wid >> 2, wn = wid & 3;     // wave grid 2M x 4N
  // XCD-chunked bijective swizzle (grid % 8 == 0)
  const int nwg = gridDim.x;
  const int cpx = nwg >> 3;
  const int swz = (blockIdx.x & 7) * cpx + (blockIdx.x >> 3);
  const int nbx = N >> 8;
  const int rblk = (swz / nbx) << 8;
  const int cblk = (swz % nbx) << 8;
  const char* Ag = (const char*)(A + (size_t)rblk * K);
  const char* Wg = (const char*)(W + (size_t)cblk * K);
  // per-lane staging source offsets (fragment-major gather):
  // subtile s = wid*2+j holds rows s*16..+15, lane l -> row s*16+(l&15),
  // k-bytes (l>>4)*16 .. +15
  int a_off[2];
#pragma unroll
  for (int j = 0; j < 2; j++) {
    int s = wid * 2 + j;
    a_off[j] = (s * 16 + lr) * (K * 2) + lg * 16;
  }
  f32x4 acc[8][4] = {};
  const int NT = K >> 5;  // K-tiles of 32

#define STAGE256(t, p)                                                             \
  {                                                                                \
    int kb = (t) << 6;                                                             \
    _Pragma("unroll") for (int j = 0; j < 2; j++) {                                \
      int s = wid * 2 + j;                                                         \
      __builtin_amdgcn_global_load_lds(GLB_PTR(Ag + a_off[j] + kb),                \
                                       LDS_PTR((char*)ldsbuf[p][0] + s * 1024),    \
                                       16, 0, 0);                                  \
      __builtin_amdgcn_global_load_lds(GLB_PTR(Wg + a_off[j] + kb),                \
                                       LDS_PTR((char*)ldsbuf[p][1] + s * 1024),    \
                                       16, 0, 0);                                  \
    }                                                                              \
  }

  STAGE256(0, 0);
  __syncthreads();
  for (int t = 0; t < NT; ++t) {
    int p = t & 1;
    if (t + 1 < NT) STAGE256(t + 1, p ^ 1);
    const char* la = (const char*)ldsbuf[p][0];
    const char* lb = (const char*)ldsbuf[p][1];
#pragma unroll
    for (int q = 0; q < 4; ++q) {
      const int mq = q >> 1, nq = q & 1;
      s16x8 af[4], bf[2];
#pragma unroll
      for (int m = 0; m < 4; m++)
        af[m] = *reinterpret_cast<const s16x8*>(la + (wm * 8 + mq * 4 + m) * 1024 + lane * 16);
#pragma unroll
      for (int n = 0; n < 2; n++)
        bf[n] = *reinterpret_cast<const s16x8*>(lb + (wn * 4 + nq * 2 + n) * 1024 + lane * 16);
      __builtin_amdgcn_s_setprio(1);
#pragma unroll
      for (int m = 0; m < 4; m++)
#pragma unroll
        for (int n = 0; n < 2; n++)
          acc[mq * 4 + m][nq * 2 + n] = __builtin_amdgcn_mfma_f32_16x16x32_bf16(
              af[m], bf[n], acc[mq * 4 + m][nq * 2 + n], 0, 0, 0);
      __builtin_amdgcn_s_setprio(0);
      if (q < 3) __builtin_amdgcn_s_barrier();
    }
    __syncthreads();  // drains vmcnt(0): tile t+1 (issued a full tile ago) landed
  }
#pragma unroll
  for (int mf = 0; mf < 8; mf++)
#pragma unroll
    for (int nf = 0; nf < 4; nf++)
#pragma unroll
      for (int r = 0; r < 4; r++) {
        int row = rblk + wm * 128 + mf * 16 + lg * 4 + r;
        int col = cblk + wn * 64 + nf * 16 + lr;
        float val = acc[mf][nf][r];
        if constexpr (BF16OUT) ((short*)Cv)[(size_t)row * N + col] = f2bf(val);
        else                   ((float*)Cv)[(size_t)row * N + col] = val;
      }
}

// m97-structure GEMM kept for the out-projection (N=1024 -> needs small tiles)
template<int BM, bool BF16OUT>
__global__ __launch_bounds__(256) void gemm_lds(const short* __restrict__ A,
                                                const short* __restrict__ W,
                                                void* __restrict__ Cv, int N, int K) {
  constexpr int BK = 32;
  constexpr int MFR = BM / 32;
  __shared__ __align__(16) short As[BM * BK];
  __shared__ __align__(16) short Bs[128 * BK];
  const int lane = threadIdx.x & 63;
  const int wid  = threadIdx.x >> 6;
  const int lr = lane & 15, lg = lane >> 4;
  const int rblk = blockIdx.y * BM;
  const int cblk = blockIdx.x * 128;
  const int wrow = (wid >> 1) * (BM / 2);
  const int wcol = (wid & 1) * 64;
  const int srow = lane >> 2;
  const int scol = (lane & 3) * 8;
  f32x4 acc[MFR][4] = {};

  for (int kk = 0; kk < K; kk += BK) {
#pragma unroll
    for (int j = 0; j < BM / 64; j++) {
      int seg = wid * (BM / 64) + j;
      const short* g = A + (size_t)(rblk + seg * 16 + srow) * K + kk + scol;
      __builtin_amdgcn_global_load_lds(GLB_PTR(g), LDS_PTR(&As[seg * 512]), 16, 0, 0);
    }
#pragma unroll
    for (int j = 0; j < 2; j++) {
      int seg = wid * 2 + j;
      const short* g = W + (size_t)(cblk + seg * 16 + srow) * K + kk + scol;
      __builtin_amdgcn_global_load_lds(GLB_PTR(g), LDS_PTR(&Bs[seg * 512]), 16, 0, 0);
    }
    __syncthreads();
    s16x8 af[MFR], bfr[4];
#pragma unroll
    for (int m = 0; m < MFR; m++)
      af[m] = *reinterpret_cast<const s16x8*>(&As[(wrow + m * 16 + lr) * BK + lg * 8]);
#pragma unroll
    for (int n = 0; n < 4; n++)
      bfr[n] = *reinterpret_cast<const s16x8*>(&Bs[(wcol + n * 16 + lr) * BK + lg * 8]);
#pragma unroll
    for (int m = 0; m < MFR; m++)
#pragma unroll
      for (int n = 0; n < 4; n++)
        acc[m][n] = __builtin_amdgcn_mfma_f32_16x16x32_bf16(af[m], bfr[n], acc[m][n], 0, 0, 0);
    __syncthreads();
  }
#pragma unroll
  for (int m = 0; m < MFR; m++)
#pragma unroll
    for (int n = 0; n < 4; n++)
#pragma unroll
      for (int r = 0; r < 4; r++) {
        int row = rblk + wrow + m * 16 + lg * 4 + r;
        int col = cblk + wcol + n * 16 + lr;
        float val = acc[m][n][r];
        if constexpr (BF16OUT) ((short*)Cv)[(size_t)row * N + col] = f2bf(val);
        else                   ((float*)Cv)[(size_t)row * N + col] = val;
      }
}

// proj (bf16, [B][T][3][H][D]) -> RoPE -> Qb/Kb ([B][H][T][D]) and Vt ([B][H][D][T])
__global__ __launch_bounds__(256) void rope_v2(const short* __restrict__ proj,
                                               short* __restrict__ Qb,
                                               short* __restrict__ Kb,
                                               short* __restrict__ Vt) {
  int tid = threadIdx.x;
  int t0 = blockIdx.x * 64;
  int bh = blockIdx.y;
  int b = bh >> 4, h = bh & 15;
  __shared__ short vtile[64 * 66];
  int i = tid & 31;
  int trow = tid >> 5;
  float freq = __expf(-(float)i * 0.2878231366f);  // ln(10000)/32
#pragma unroll
  for (int it = 0; it < 8; ++it) {
    int tl = it * 8 + trow;
    int t = t0 + tl;
    int pbase = (b * TT + t) * 3 * EMB + h * HD + 2 * i;
    unsigned q01 = *reinterpret_cast<const unsigned*>(proj + pbase);
    unsigned k01 = *reinterpret_cast<const unsigned*>(proj + pbase + EMB);
    unsigned v01 = *reinterpret_cast<const unsigned*>(proj + pbase + 2 * EMB);
    float qa = bf2f((unsigned short)(q01 & 0xffff)), qb_ = bf2f((unsigned short)(q01 >> 16));
    float ka = bf2f((unsigned short)(k01 & 0xffff)), kb_ = bf2f((unsigned short)(k01 >> 16));
    float ang = (float)t * freq;
    float s, c;
    sincosf(ang, &s, &c);
    int obase = (bh * TT + t) * HD + 2 * i;
    unsigned qo = ((unsigned)(unsigned short)f2bf(qa * s + qb_ * c) << 16) |
                  (unsigned short)f2bf(qa * c - qb_ * s);
    unsigned ko = ((unsigned)(unsigned short)f2bf(ka * s + kb_ * c) << 16) |
                  (unsigned short)f2bf(ka * c - kb_ * s);
    *reinterpret_cast<unsigned*>(Qb + obase) = qo;
    *reinterpret_cast<unsigned*>(Kb + obase) = ko;
    *reinterpret_cast<unsigned*>(&vtile[tl * 66 + 2 * i]) = v01;
  }
  __syncthreads();
  int d = tid >> 2, toff = (tid & 3) * 16;
  s16x8 o0, o1;
#pragma unroll
  for (int j = 0; j < 8; ++j) {
    o0[j] = vtile[(toff + j) * 66 + d];
    o1[j] = vtile[(toff + 8 + j) * 66 + d];
  }
  size_t vb = (size_t)(bh * HD + d) * TT + t0 + toff;
  *reinterpret_cast<s16x8*>(Vt + vb) = o0;
  *reinterpret_cast<s16x8*>(Vt + vb + 8) = o1;
}

// 4-wave blocks: 64 q-rows/block, K/V tiles staged once per block into
// swizzled LDS. XCD-chunked block mapping: 8 XCDs x 4 bh x 32 t-blocks.
__global__ __launch_bounds__(256) void attn_v3(const short* __restrict__ Qb,
                                               const short* __restrict__ Kb,
                                               const short* __restrict__ Vt,
                                               short* __restrict__ Xout) {
  const float NEG = -3.0e38f;
  int tid = threadIdx.x;
  int lane = tid & 63;
  int w = tid >> 6;
  int lr = lane & 15, lg = lane >> 4;
  int id = blockIdx.x;
  int xcd = id & 7;
  int sub = id >> 3;
  int bh = xcd * 4 + (sub >> 5);
  int tblk = (sub & 31) * 64;
  int t0 = tblk + w * 16;
  int b = bh >> 4, h = bh & 15;
  const short* Qp = Qb + bh * TT * HD;
  const char* Kp = (const char*)(Kb + bh * TT * HD);
  const char* Vtp = (const char*)(Vt + bh * HD * TT);
  __shared__ __align__(16) short Ks[32 * 64];
  __shared__ __align__(16) short Vs[64 * 32];
  __shared__ __align__(16) short p_lds[4][16][40];
  s16x8 qf[2];
#pragma unroll
  for (int d2 = 0; d2 < 2; d2++)
    qf[d2] = *reinterpret_cast<const s16x8*>(Qp + (t0 + lr) * HD + d2 * 32 + lg * 8);
  f32x4 of[4] = {};
  float m_run[4], l_run[4];
#pragma unroll
  for (int r = 0; r < 4; r++) { m_run[r] = NEG; l_run[r] = 0.0f; }
  int lo = tblk - (CTX - 1); if (lo < 0) lo = 0;
  int kt_lo = lo & ~31;
  int kt_hi = (tblk + 63) & ~31;
  int krow = w * 8 + (lane >> 3);
  int kcb  = ((lane & 7) * 16) ^ ((krow & 7) << 4);
  int vd   = w * 16 + (lane >> 2);
  int vcb  = ((lane & 3) * 16) ^ (((vd >> 1) & 3) << 4);
  char* ksdst = (char*)Ks + w * 1024 + lane * 16;
  char* vsdst = (char*)Vs + w * 1024 + lane * 16;
  for (int kt = kt_lo; kt <= kt_hi; kt += 32) {
    __builtin_amdgcn_global_load_lds(GLB_PTR(Kp + (kt + krow) * 128 + kcb),
                                     LDS_PTR(ksdst), 16, 0, 0);
    __builtin_amdgcn_global_load_lds(GLB_PTR(Vtp + vd * (TT * 2) + kt * 2 + vcb),
                                     LDS_PTR(vsdst), 16, 0, 0);
    __syncthreads();
    if (kt <= t0 + 15 && kt + 31 >= t0 - (CTX - 1)) {
      f32x4 s2[2];
#pragma unroll
      for (int hh = 0; hh < 2; hh++) {
        int row = hh * 16 + lr;
        f32x4 sa = {};
#pragma unroll
        for (int d2 = 0; d2 < 2; d2++) {
          int cb = (d2 * 64 + lg * 16) ^ ((row & 7) << 4);
          s16x8 kf = *reinterpret_cast<const s16x8*>((const char*)Ks + row * 128 + cb);
          sa = __builtin_amdgcn_mfma_f32_16x16x32_bf16(qf[d2], kf, sa, 0, 0, 0);
        }
        s2[hh] = sa;
      }
#pragma unroll
      for (int r = 0; r < 4; r++) {
        int row = t0 + lg * 4 + r;
        float sv[2]; bool vdm[2];
#pragma unroll
        for (int hh = 0; hh < 2; hh++) {
          int col = kt + hh * 16 + lr;
          int dl = row - col;
          vdm[hh] = (dl >= 0) && (dl < CTX);
          sv[hh] = vdm[hh] ? s2[hh][r] * 0.125f : NEG;
        }
        float mx = fmaxf(sv[0], sv[1]);
#pragma unroll
        for (int off = 1; off < 16; off <<= 1) mx = fmaxf(mx, __shfl_xor(mx, off, 16));
        float mnew = fmaxf(m_run[r], mx);
        float corr = __expf(m_run[r] - mnew);
        float psum = 0.0f;
#pragma unroll
        for (int hh = 0; hh < 2; hh++) {
          float p = vdm[hh] ? __expf(sv[hh] - mnew) : 0.0f;
          p_lds[w][lg * 4 + r][hh * 16 + lr] = f2bf(p);
          psum += p;
        }
#pragma unroll
        for (int off = 1; off < 16; off <<= 1) psum += __shfl_xor(psum, off, 16);
        l_run[r] = l_run[r] * corr + psum;
        m_run[r] = mnew;
#pragma unroll
        for (int n = 0; n < 4; n++) of[n][r] *= corr;
      }
      s16x8 pa = *reinterpret_cast<const s16x8*>(&p_lds[w][lr][lg * 8]);
#pragma unroll
      for (int n = 0; n < 4; n++) {
        int d = n * 16 + lr;
        int cb = (lg * 16) ^ (((d >> 1) & 3) << 4);
        s16x8 vf = *reinterpret_cast<const s16x8*>((const char*)Vs + d * 64 + cb);
        of[n] = __builtin_amdgcn_mfma_f32_16x16x32_bf16(pa, vf, of[n], 0, 0, 0);
      }
    }
    __syncthreads();
  }
#pragma unroll
  for (int r = 0; r < 4; r++) {
    float inv = 1.0f / l_run[r];
    int row = t0 + lg * 4 + r;
#pragma unroll
    for (int n = 0; n < 4; n++)
      Xout[(b * TT + row) * EMB + h * HD + n * 16 + lr] = f2bf(of[n][r] * inv);
  }
}

extern "C" void kernel_launch(void* const* d_in, const int* in_sizes, int n_in,
                              void* d_out, int out_size, void* d_ws, size_t ws_size,
                              hipStream_t stream) {
  const float* query = (const float*)d_in[0];
  const float* w_in  = (const float*)d_in[1];
  const float* w_out = (const float*)d_in[2];
  char* ws = (char*)d_ws;
  short* qbf   = (short*)(ws + 0);          //  8388608  query bf16 [4096][1024]
  short* wibf  = (short*)(ws + 8388608);    //  6291456  in_proj bf16 [3072][1024]
  short* wobf  = (short*)(ws + 14680064);   //  2097152  out_proj bf16 [1024][1024]
  short* proj  = (short*)(ws + 16777216);   // 25165824  qkv proj bf16 [4096][3072]
  short* attnx = (short*)(ws + 16777216);   // alias: proj dead after rope
  short* Qb    = (short*)(ws + 41943040);   //  8388608  [B][H][T][D]
  short* Kb    = (short*)(ws + 50331648);   //  8388608  [B][H][T][D]
  short* Vt    = (short*)(ws + 58720256);   //  8388608  [B][H][D][T]

  cvt_all<<<8192, 256, 0, stream>>>(query, w_in, w_out, qbf, wibf, wobf);
  gemm_256<true><<<192, 512, 0, stream>>>(qbf, wibf, (void*)proj, 3072, 1024);
  rope_v2<<<dim3(32, 32), 256, 0, stream>>>(proj, Qb, Kb, Vt);
  attn_v3<<<1024, 256, 0, stream>>>(Qb, Kb, Vt, attnx);
  gemm_lds<64, false><<<dim3(8, 64), 256, 0, stream>>>(attnx, wobf, d_out, 1024, 1024);
}

// Round 7
// 111.675 us; speedup vs baseline: 1.0520x; 1.0520x over previous
//
#include <hip/hip_runtime.h>

#define TT 2048
#define EMB 1024
#define NH 16
#define HD 64
#define CTX 250

typedef __attribute__((ext_vector_type(4))) float f32x4;
typedef __attribute__((ext_vector_type(8))) short s16x8;
typedef __attribute__((ext_vector_type(4))) short s16x4;

#define LDS_PTR(p) ((__attribute__((address_space(3))) void*)(p))
#define GLB_PTR(p) ((const __attribute__((address_space(1))) void*)(p))

__device__ __forceinline__ short f2bf(float f) {
  union { float f; unsigned u; } v; v.f = f;
  unsigned r = v.u + 0x7fffu + ((v.u >> 16) & 1u);
  return (short)(r >> 16);
}
__device__ __forceinline__ float bf2f(unsigned short u) {
  union { unsigned u; float f; } v; v.u = ((unsigned)u) << 16;
  return v.f;
}

// one kernel converts all three f32 inputs to bf16
// segments (float4 units): q = 1048576, wi = 786432, wo = 262144; total 2097152
__global__ void cvt_all(const float* __restrict__ q, const float* __restrict__ wi,
                        const float* __restrict__ wo, short* __restrict__ qo,
                        short* __restrict__ wio, short* __restrict__ woo) {
  int i = blockIdx.x * blockDim.x + threadIdx.x;
  const float* src; short* dst; int off;
  if (i < 1048576)      { src = q;  dst = qo;  off = i; }
  else if (i < 1835008) { src = wi; dst = wio; off = i - 1048576; }
  else                  { src = wo; dst = woo; off = i - 1835008; }
  float4 v = reinterpret_cast<const float4*>(src)[off];
  s16x4 o; o[0] = f2bf(v.x); o[1] = f2bf(v.y); o[2] = f2bf(v.z); o[3] = f2bf(v.w);
  *reinterpret_cast<s16x4*>(dst + off * 4) = o;
}

// ---------------------------------------------------------------------------
// 256x256 GEMM, BK=32, 8 waves (2M x 4N), RING-3 LDS + counted vmcnt (T4).
// Fragment-major LDS (16x32 subtiles of 1KB; ds_read = base + lane*16,
// conflict-free, verified 0 SQ_LDS_BANK_CONFLICT in R6).
// Pipeline: stages t+1, t+2 in flight; loop top waits vmcnt(4) (stage t done,
// stage t+1 still flying) -> raw s_barrier -> issue stage t+2 -> compute t.
// vmcnt never drains to 0 in the main loop (m218 lever). Ring-3 WAR safe:
// buf[(t+2)%3] == buf[(t-1)%3], whose readers all passed the barrier.
// ---------------------------------------------------------------------------
template<bool BF16OUT>
__global__ __launch_bounds__(512, 1) void gemm_256(const short* __restrict__ A,
                                                   const short* __restrict__ W,
                                                   void* __restrict__ Cv, int N, int K) {
  __shared__ __align__(16) short ldsbuf[3][2][8192];  // [ring][A/B][16 subtiles x 512]
  const int tid = threadIdx.x;
  const int lane = tid & 63;
  const int wid = tid >> 6;
  const int lr = lane & 15, lg = lane >> 4;
  const int wm = wid >> 2, wn = wid & 3;     // wave grid 2M x 4N
  // XCD-chunked bijective swizzle (grid % 8 == 0)
  const int nwg = gridDim.x;
  const int cpx = nwg >> 3;
  const int swz = (blockIdx.x & 7) * cpx + (blockIdx.x >> 3);
  const int nbx = N >> 8;
  const int rblk = (swz / nbx) << 8;
  const int cblk = (swz % nbx) << 8;
  const char* Ag = (const char*)(A + (size_t)rblk * K);
  const char* Wg = (const char*)(W + (size_t)cblk * K);
  // fragment-major gather: subtile s holds rows s*16..+15; lane l -> row
  // s*16+(l&15), k-bytes (l>>4)*16..+15
  int a_off[2];
#pragma unroll
  for (int j = 0; j < 2; j++) {
    int s = wid * 2 + j;
    a_off[j] = (s * 16 + lr) * (K * 2) + lg * 16;
  }
  f32x4 acc[8][4] = {};
  const int NT = K >> 5;  // K-tiles of 32 (NT >= 3)

#define STAGE256(t, p)                                                             \
  {                                                                                \
    int kb = (t) << 6;                                                             \
    _Pragma("unroll") for (int j = 0; j < 2; j++) {                                \
      int s = wid * 2 + j;                                                         \
      __builtin_amdgcn_global_load_lds(GLB_PTR(Ag + a_off[j] + kb),                \
                                       LDS_PTR((char*)ldsbuf[p][0] + s * 1024),    \
                                       16, 0, 0);                                  \
      __builtin_amdgcn_global_load_lds(GLB_PTR(Wg + a_off[j] + kb),                \
                                       LDS_PTR((char*)ldsbuf[p][1] + s * 1024),    \
                                       16, 0, 0);                                  \
    }                                                                              \
  }

#define COMPUTE256(p)                                                              \
  {                                                                                \
    const char* la = (const char*)ldsbuf[p][0];                                    \
    const char* lb = (const char*)ldsbuf[p][1];                                    \
    _Pragma("unroll") for (int q = 0; q < 4; ++q) {                                \
      const int mq = q >> 1, nq = q & 1;                                           \
      s16x8 af[4], bfv[2];                                                         \
      _Pragma("unroll") for (int m = 0; m < 4; m++)                                \
        af[m] = *reinterpret_cast<const s16x8*>(la + (wm * 8 + mq * 4 + m) * 1024  \
                                                + lane * 16);                      \
      _Pragma("unroll") for (int n = 0; n < 2; n++)                                \
        bfv[n] = *reinterpret_cast<const s16x8*>(lb + (wn * 4 + nq * 2 + n) * 1024 \
                                                 + lane * 16);                     \
      __builtin_amdgcn_s_setprio(1);                                               \
      _Pragma("unroll") for (int m = 0; m < 4; m++)                                \
        _Pragma("unroll") for (int n = 0; n < 2; n++)                              \
          acc[mq * 4 + m][nq * 2 + n] = __builtin_amdgcn_mfma_f32_16x16x32_bf16(   \
              af[m], bfv[n], acc[mq * 4 + m][nq * 2 + n], 0, 0, 0);                \
      __builtin_amdgcn_s_setprio(0);                                               \
      if (q < 3) __builtin_amdgcn_s_barrier();                                     \
    }                                                                              \
  }

  STAGE256(0, 0);
  STAGE256(1, 1);
  int p = 0;
  for (int t = 0; t < NT - 1; ++t) {
    asm volatile("s_waitcnt vmcnt(4)" ::: "memory");  // stage(t) done; t+1 in flight
    __builtin_amdgcn_s_barrier();                     // all waves' stage(t) visible
    __builtin_amdgcn_sched_barrier(0);
    if (t + 2 < NT) {
      int pn = p + 2; if (pn >= 3) pn -= 3;
      STAGE256(t + 2, pn);
    }
    COMPUTE256(p);
    ++p; if (p == 3) p = 0;
  }
  asm volatile("s_waitcnt vmcnt(0)" ::: "memory");    // last stage fully landed
  __builtin_amdgcn_s_barrier();
  __builtin_amdgcn_sched_barrier(0);
  COMPUTE256(p);

#pragma unroll
  for (int mf = 0; mf < 8; mf++)
#pragma unroll
    for (int nf = 0; nf < 4; nf++)
#pragma unroll
      for (int r = 0; r < 4; r++) {
        int row = rblk + wm * 128 + mf * 16 + lg * 4 + r;
        int col = cblk + wn * 64 + nf * 16 + lr;
        float val = acc[mf][nf][r];
        if constexpr (BF16OUT) ((short*)Cv)[(size_t)row * N + col] = f2bf(val);
        else                   ((float*)Cv)[(size_t)row * N + col] = val;
      }
}

// m97-structure GEMM kept for the out-projection (N=1024 -> needs small tiles)
template<int BM, bool BF16OUT>
__global__ __launch_bounds__(256) void gemm_lds(const short* __restrict__ A,
                                                const short* __restrict__ W,
                                                void* __restrict__ Cv, int N, int K) {
  constexpr int BK = 32;
  constexpr int MFR = BM / 32;
  __shared__ __align__(16) short As[BM * BK];
  __shared__ __align__(16) short Bs[128 * BK];
  const int lane = threadIdx.x & 63;
  const int wid  = threadIdx.x >> 6;
  const int lr = lane & 15, lg = lane >> 4;
  const int rblk = blockIdx.y * BM;
  const int cblk = blockIdx.x * 128;
  const int wrow = (wid >> 1) * (BM / 2);
  const int wcol = (wid & 1) * 64;
  const int srow = lane >> 2;
  const int scol = (lane & 3) * 8;
  f32x4 acc[MFR][4] = {};

  for (int kk = 0; kk < K; kk += BK) {
#pragma unroll
    for (int j = 0; j < BM / 64; j++) {
      int seg = wid * (BM / 64) + j;
      const short* g = A + (size_t)(rblk + seg * 16 + srow) * K + kk + scol;
      __builtin_amdgcn_global_load_lds(GLB_PTR(g), LDS_PTR(&As[seg * 512]), 16, 0, 0);
    }
#pragma unroll
    for (int j = 0; j < 2; j++) {
      int seg = wid * 2 + j;
      const short* g = W + (size_t)(cblk + seg * 16 + srow) * K + kk + scol;
      __builtin_amdgcn_global_load_lds(GLB_PTR(g), LDS_PTR(&Bs[seg * 512]), 16, 0, 0);
    }
    __syncthreads();
    s16x8 af[MFR], bfr[4];
#pragma unroll
    for (int m = 0; m < MFR; m++)
      af[m] = *reinterpret_cast<const s16x8*>(&As[(wrow + m * 16 + lr) * BK + lg * 8]);
#pragma unroll
    for (int n = 0; n < 4; n++)
      bfr[n] = *reinterpret_cast<const s16x8*>(&Bs[(wcol + n * 16 + lr) * BK + lg * 8]);
#pragma unroll
    for (int m = 0; m < MFR; m++)
#pragma unroll
      for (int n = 0; n < 4; n++)
        acc[m][n] = __builtin_amdgcn_mfma_f32_16x16x32_bf16(af[m], bfr[n], acc[m][n], 0, 0, 0);
    __syncthreads();
  }
#pragma unroll
  for (int m = 0; m < MFR; m++)
#pragma unroll
    for (int n = 0; n < 4; n++)
#pragma unroll
      for (int r = 0; r < 4; r++) {
        int row = rblk + wrow + m * 16 + lg * 4 + r;
        int col = cblk + wcol + n * 16 + lr;
        float val = acc[m][n][r];
        if constexpr (BF16OUT) ((short*)Cv)[(size_t)row * N + col] = f2bf(val);
        else                   ((float*)Cv)[(size_t)row * N + col] = val;
      }
}

// proj (bf16, [B][T][3][H][D]) -> RoPE -> Qb/Kb ([B][H][T][D]) and Vt ([B][H][D][T])
__global__ __launch_bounds__(256) void rope_v2(const short* __restrict__ proj,
                                               short* __restrict__ Qb,
                                               short* __restrict__ Kb,
                                               short* __restrict__ Vt) {
  int tid = threadIdx.x;
  int t0 = blockIdx.x * 64;
  int bh = blockIdx.y;
  int b = bh >> 4, h = bh & 15;
  __shared__ short vtile[64 * 66];
  int i = tid & 31;
  int trow = tid >> 5;
  float freq = __expf(-(float)i * 0.2878231366f);  // ln(10000)/32
#pragma unroll
  for (int it = 0; it < 8; ++it) {
    int tl = it * 8 + trow;
    int t = t0 + tl;
    int pbase = (b * TT + t) * 3 * EMB + h * HD + 2 * i;
    unsigned q01 = *reinterpret_cast<const unsigned*>(proj + pbase);
    unsigned k01 = *reinterpret_cast<const unsigned*>(proj + pbase + EMB);
    unsigned v01 = *reinterpret_cast<const unsigned*>(proj + pbase + 2 * EMB);
    float qa = bf2f((unsigned short)(q01 & 0xffff)), qb_ = bf2f((unsigned short)(q01 >> 16));
    float ka = bf2f((unsigned short)(k01 & 0xffff)), kb_ = bf2f((unsigned short)(k01 >> 16));
    float ang = (float)t * freq;
    float s, c;
    sincosf(ang, &s, &c);
    int obase = (bh * TT + t) * HD + 2 * i;
    unsigned qo = ((unsigned)(unsigned short)f2bf(qa * s + qb_ * c) << 16) |
                  (unsigned short)f2bf(qa * c - qb_ * s);
    unsigned ko = ((unsigned)(unsigned short)f2bf(ka * s + kb_ * c) << 16) |
                  (unsigned short)f2bf(ka * c - kb_ * s);
    *reinterpret_cast<unsigned*>(Qb + obase) = qo;
    *reinterpret_cast<unsigned*>(Kb + obase) = ko;
    *reinterpret_cast<unsigned*>(&vtile[tl * 66 + 2 * i]) = v01;
  }
  __syncthreads();
  int d = tid >> 2, toff = (tid & 3) * 16;
  s16x8 o0, o1;
#pragma unroll
  for (int j = 0; j < 8; ++j) {
    o0[j] = vtile[(toff + j) * 66 + d];
    o1[j] = vtile[(toff + 8 + j) * 66 + d];
  }
  size_t vb = (size_t)(bh * HD + d) * TT + t0 + toff;
  *reinterpret_cast<s16x8*>(Vt + vb) = o0;
  *reinterpret_cast<s16x8*>(Vt + vb + 8) = o1;
}

// 4-wave blocks: 64 q-rows/block, K/V tiles staged once per block into
// swizzled LDS. XCD-chunked block mapping: 8 XCDs x 4 bh x 32 t-blocks.
__global__ __launch_bounds__(256) void attn_v3(const short* __restrict__ Qb,
                                               const short* __restrict__ Kb,
                                               const short* __restrict__ Vt,
                                               short* __restrict__ Xout) {
  const float NEG = -3.0e38f;
  int tid = threadIdx.x;
  int lane = tid & 63;
  int w = tid >> 6;
  int lr = lane & 15, lg = lane >> 4;
  int id = blockIdx.x;
  int xcd = id & 7;
  int sub = id >> 3;
  int bh = xcd * 4 + (sub >> 5);
  int tblk = (sub & 31) * 64;
  int t0 = tblk + w * 16;
  int b = bh >> 4, h = bh & 15;
  const short* Qp = Qb + bh * TT * HD;
  const char* Kp = (const char*)(Kb + bh * TT * HD);
  const char* Vtp = (const char*)(Vt + bh * HD * TT);
  __shared__ __align__(16) short Ks[32 * 64];
  __shared__ __align__(16) short Vs[64 * 32];
  __shared__ __align__(16) short p_lds[4][16][40];
  s16x8 qf[2];
#pragma unroll
  for (int d2 = 0; d2 < 2; d2++)
    qf[d2] = *reinterpret_cast<const s16x8*>(Qp + (t0 + lr) * HD + d2 * 32 + lg * 8);
  f32x4 of[4] = {};
  float m_run[4], l_run[4];
#pragma unroll
  for (int r = 0; r < 4; r++) { m_run[r] = NEG; l_run[r] = 0.0f; }
  int lo = tblk - (CTX - 1); if (lo < 0) lo = 0;
  int kt_lo = lo & ~31;
  int kt_hi = (tblk + 63) & ~31;
  int krow = w * 8 + (lane >> 3);
  int kcb  = ((lane & 7) * 16) ^ ((krow & 7) << 4);
  int vd   = w * 16 + (lane >> 2);
  int vcb  = ((lane & 3) * 16) ^ (((vd >> 1) & 3) << 4);
  char* ksdst = (char*)Ks + w * 1024 + lane * 16;
  char* vsdst = (char*)Vs + w * 1024 + lane * 16;
  for (int kt = kt_lo; kt <= kt_hi; kt += 32) {
    __builtin_amdgcn_global_load_lds(GLB_PTR(Kp + (kt + krow) * 128 + kcb),
                                     LDS_PTR(ksdst), 16, 0, 0);
    __builtin_amdgcn_global_load_lds(GLB_PTR(Vtp + vd * (TT * 2) + kt * 2 + vcb),
                                     LDS_PTR(vsdst), 16, 0, 0);
    __syncthreads();
    if (kt <= t0 + 15 && kt + 31 >= t0 - (CTX - 1)) {
      f32x4 s2[2];
#pragma unroll
      for (int hh = 0; hh < 2; hh++) {
        int row = hh * 16 + lr;
        f32x4 sa = {};
#pragma unroll
        for (int d2 = 0; d2 < 2; d2++) {
          int cb = (d2 * 64 + lg * 16) ^ ((row & 7) << 4);
          s16x8 kf = *reinterpret_cast<const s16x8*>((const char*)Ks + row * 128 + cb);
          sa = __builtin_amdgcn_mfma_f32_16x16x32_bf16(qf[d2], kf, sa, 0, 0, 0);
        }
        s2[hh] = sa;
      }
#pragma unroll
      for (int r = 0; r < 4; r++) {
        int row = t0 + lg * 4 + r;
        float sv[2]; bool vdm[2];
#pragma unroll
        for (int hh = 0; hh < 2; hh++) {
          int col = kt + hh * 16 + lr;
          int dl = row - col;
          vdm[hh] = (dl >= 0) && (dl < CTX);
          sv[hh] = vdm[hh] ? s2[hh][r] * 0.125f : NEG;
        }
        float mx = fmaxf(sv[0], sv[1]);
#pragma unroll
        for (int off = 1; off < 16; off <<= 1) mx = fmaxf(mx, __shfl_xor(mx, off, 16));
        float mnew = fmaxf(m_run[r], mx);
        float corr = __expf(m_run[r] - mnew);
        float psum = 0.0f;
#pragma unroll
        for (int hh = 0; hh < 2; hh++) {
          float pv = vdm[hh] ? __expf(sv[hh] - mnew) : 0.0f;
          p_lds[w][lg * 4 + r][hh * 16 + lr] = f2bf(pv);
          psum += pv;
        }
#pragma unroll
        for (int off = 1; off < 16; off <<= 1) psum += __shfl_xor(psum, off, 16);
        l_run[r] = l_run[r] * corr + psum;
        m_run[r] = mnew;
#pragma unroll
        for (int n = 0; n < 4; n++) of[n][r] *= corr;
      }
      s16x8 pa = *reinterpret_cast<const s16x8*>(&p_lds[w][lr][lg * 8]);
#pragma unroll
      for (int n = 0; n < 4; n++) {
        int d = n * 16 + lr;
        int cb = (lg * 16) ^ (((d >> 1) & 3) << 4);
        s16x8 vf = *reinterpret_cast<const s16x8*>((const char*)Vs + d * 64 + cb);
        of[n] = __builtin_amdgcn_mfma_f32_16x16x32_bf16(pa, vf, of[n], 0, 0, 0);
      }
    }
    __syncthreads();
  }
#pragma unroll
  for (int r = 0; r < 4; r++) {
    float inv = 1.0f / l_run[r];
    int row = t0 + lg * 4 + r;
#pragma unroll
    for (int n = 0; n < 4; n++)
      Xout[(b * TT + row) * EMB + h * HD + n * 16 + lr] = f2bf(of[n][r] * inv);
  }
}

extern "C" void kernel_launch(void* const* d_in, const int* in_sizes, int n_in,
                              void* d_out, int out_size, void* d_ws, size_t ws_size,
                              hipStream_t stream) {
  const float* query = (const float*)d_in[0];
  const float* w_in  = (const float*)d_in[1];
  const float* w_out = (const float*)d_in[2];
  char* ws = (char*)d_ws;
  short* qbf   = (short*)(ws + 0);          //  8388608  query bf16 [4096][1024]
  short* wibf  = (short*)(ws + 8388608);    //  6291456  in_proj bf16 [3072][1024]
  short* wobf  = (short*)(ws + 14680064);   //  2097152  out_proj bf16 [1024][1024]
  short* proj  = (short*)(ws + 16777216);   // 25165824  qkv proj bf16 [4096][3072]
  short* attnx = (short*)(ws + 16777216);   // alias: proj dead after rope
  short* Qb    = (short*)(ws + 41943040);   //  8388608  [B][H][T][D]
  short* Kb    = (short*)(ws + 50331648);   //  8388608  [B][H][T][D]
  short* Vt    = (short*)(ws + 58720256);   //  8388608  [B][H][D][T]

  cvt_all<<<8192, 256, 0, stream>>>(query, w_in, w_out, qbf, wibf, wobf);
  gemm_256<true><<<192, 512, 0, stream>>>(qbf, wibf, (void*)proj, 3072, 1024);
  rope_v2<<<dim3(32, 32), 256, 0, stream>>>(proj, Qb, Kb, Vt);
  attn_v3<<<1024, 256, 0, stream>>>(Qb, Kb, Vt, attnx);
  gemm_lds<64, false><<<dim3(8, 64), 256, 0, stream>>>(attnx, wobf, d_out, 1024, 1024);
}

// Round 8
// 110.179 us; speedup vs baseline: 1.0663x; 1.0136x over previous
//
#include <hip/hip_runtime.h>

#define TT 2048
#define EMB 1024
#define NH 16
#define HD 64
#define CTX 250

typedef __attribute__((ext_vector_type(4))) float f32x4;
typedef __attribute__((ext_vector_type(8))) short s16x8;
typedef __attribute__((ext_vector_type(4))) short s16x4;

#define LDS_PTR(p) ((__attribute__((address_space(3))) void*)(p))
#define GLB_PTR(p) ((const __attribute__((address_space(1))) void*)(p))

__device__ __forceinline__ short f2bf(float f) {
  union { float f; unsigned u; } v; v.f = f;
  unsigned r = v.u + 0x7fffu + ((v.u >> 16) & 1u);
  return (short)(r >> 16);
}
__device__ __forceinline__ float bf2f(unsigned short u) {
  union { unsigned u; float f; } v; v.u = ((unsigned)u) << 16;
  return v.f;
}

// one kernel converts all three f32 inputs to bf16
// segments (float4 units): q = 1048576, wi = 786432, wo = 262144; total 2097152
__global__ void cvt_all(const float* __restrict__ q, const float* __restrict__ wi,
                        const float* __restrict__ wo, short* __restrict__ qo,
                        short* __restrict__ wio, short* __restrict__ woo) {
  int i = blockIdx.x * blockDim.x + threadIdx.x;
  const float* src; short* dst; int off;
  if (i < 1048576)      { src = q;  dst = qo;  off = i; }
  else if (i < 1835008) { src = wi; dst = wio; off = i - 1048576; }
  else                  { src = wo; dst = woo; off = i - 1835008; }
  float4 v = reinterpret_cast<const float4*>(src)[off];
  s16x4 o; o[0] = f2bf(v.x); o[1] = f2bf(v.y); o[2] = f2bf(v.z); o[3] = f2bf(v.w);
  *reinterpret_cast<s16x4*>(dst + off * 4) = o;
}

// ---------------------------------------------------------------------------
// 256x256 GEMM, BK=32, 8 waves (2M x 4N), RING-3 LDS + counted vmcnt.
// Fragment-major LDS (16x32 subtiles of 1KB; ds_read = base + lane*16,
// conflict-free — 0 SQ_LDS_BANK_CONFLICT measured).
// R8 change: single compute phase per K-tile — af[8]+bf[4] loaded ONCE
// (12 ds_read_b128/wave/tile, was 24), one 32-MFMA cluster, 1 barrier/tile
// (was 4). LDS-read traffic per CU halves: that was the measured bottleneck.
// ---------------------------------------------------------------------------
template<bool BF16OUT>
__global__ __launch_bounds__(512, 1) void gemm_256(const short* __restrict__ A,
                                                   const short* __restrict__ W,
                                                   void* __restrict__ Cv, int N, int K) {
  __shared__ __align__(16) short ldsbuf[3][2][8192];  // [ring][A/B][16 subtiles x 512]
  const int tid = threadIdx.x;
  const int lane = tid & 63;
  const int wid = tid >> 6;
  const int lr = lane & 15, lg = lane >> 4;
  const int wm = wid >> 2, wn = wid & 3;     // wave grid 2M x 4N
  // XCD-chunked bijective swizzle (grid % 8 == 0)
  const int nwg = gridDim.x;
  const int cpx = nwg >> 3;
  const int swz = (blockIdx.x & 7) * cpx + (blockIdx.x >> 3);
  const int nbx = N >> 8;
  const int rblk = (swz / nbx) << 8;
  const int cblk = (swz % nbx) << 8;
  const char* Ag = (const char*)(A + (size_t)rblk * K);
  const char* Wg = (const char*)(W + (size_t)cblk * K);
  // fragment-major gather: subtile s holds rows s*16..+15; lane l -> row
  // s*16+(l&15), k-bytes (l>>4)*16..+15
  int a_off[2];
#pragma unroll
  for (int j = 0; j < 2; j++) {
    int s = wid * 2 + j;
    a_off[j] = (s * 16 + lr) * (K * 2) + lg * 16;
  }
  f32x4 acc[8][4] = {};
  const int NT = K >> 5;  // K-tiles of 32 (NT >= 3)

#define STAGE256(t, p)                                                             \
  {                                                                                \
    int kb = (t) << 6;                                                             \
    _Pragma("unroll") for (int j = 0; j < 2; j++) {                                \
      int s = wid * 2 + j;                                                         \
      __builtin_amdgcn_global_load_lds(GLB_PTR(Ag + a_off[j] + kb),                \
                                       LDS_PTR((char*)ldsbuf[p][0] + s * 1024),    \
                                       16, 0, 0);                                  \
      __builtin_amdgcn_global_load_lds(GLB_PTR(Wg + a_off[j] + kb),                \
                                       LDS_PTR((char*)ldsbuf[p][1] + s * 1024),    \
                                       16, 0, 0);                                  \
    }                                                                              \
  }

  // single phase: all fragments once, one MFMA cluster
#define COMPUTE256(p)                                                              \
  {                                                                                \
    const char* la = (const char*)ldsbuf[p][0];                                    \
    const char* lb = (const char*)ldsbuf[p][1];                                    \
    s16x8 af[8], bfv[4];                                                           \
    _Pragma("unroll") for (int m = 0; m < 8; m++)                                  \
      af[m] = *reinterpret_cast<const s16x8*>(la + (wm * 8 + m) * 1024             \
                                              + lane * 16);                        \
    _Pragma("unroll") for (int n = 0; n < 4; n++)                                  \
      bfv[n] = *reinterpret_cast<const s16x8*>(lb + (wn * 4 + n) * 1024            \
                                               + lane * 16);                       \
    __builtin_amdgcn_s_setprio(1);                                                 \
    _Pragma("unroll") for (int m = 0; m < 8; m++)                                  \
      _Pragma("unroll") for (int n = 0; n < 4; n++)                                \
        acc[m][n] = __builtin_amdgcn_mfma_f32_16x16x32_bf16(                       \
            af[m], bfv[n], acc[m][n], 0, 0, 0);                                    \
    __builtin_amdgcn_s_setprio(0);                                                 \
  }

  STAGE256(0, 0);
  STAGE256(1, 1);
  int p = 0;
  for (int t = 0; t < NT - 1; ++t) {
    asm volatile("s_waitcnt vmcnt(4)" ::: "memory");  // stage(t) done; t+1 in flight
    __builtin_amdgcn_s_barrier();                     // all waves' stage(t) visible
    __builtin_amdgcn_sched_barrier(0);
    if (t + 2 < NT) {
      int pn = p + 2; if (pn >= 3) pn -= 3;
      STAGE256(t + 2, pn);
    }
    COMPUTE256(p);
    ++p; if (p == 3) p = 0;
  }
  asm volatile("s_waitcnt vmcnt(0)" ::: "memory");    // last stage fully landed
  __builtin_amdgcn_s_barrier();
  __builtin_amdgcn_sched_barrier(0);
  COMPUTE256(p);

#pragma unroll
  for (int mf = 0; mf < 8; mf++)
#pragma unroll
    for (int nf = 0; nf < 4; nf++)
#pragma unroll
      for (int r = 0; r < 4; r++) {
        int row = rblk + wm * 128 + mf * 16 + lg * 4 + r;
        int col = cblk + wn * 64 + nf * 16 + lr;
        float val = acc[mf][nf][r];
        if constexpr (BF16OUT) ((short*)Cv)[(size_t)row * N + col] = f2bf(val);
        else                   ((float*)Cv)[(size_t)row * N + col] = val;
      }
}

// m97-structure GEMM kept for the out-projection (N=1024 -> needs small tiles)
template<int BM, bool BF16OUT>
__global__ __launch_bounds__(256) void gemm_lds(const short* __restrict__ A,
                                                const short* __restrict__ W,
                                                void* __restrict__ Cv, int N, int K) {
  constexpr int BK = 32;
  constexpr int MFR = BM / 32;
  __shared__ __align__(16) short As[BM * BK];
  __shared__ __align__(16) short Bs[128 * BK];
  const int lane = threadIdx.x & 63;
  const int wid  = threadIdx.x >> 6;
  const int lr = lane & 15, lg = lane >> 4;
  const int rblk = blockIdx.y * BM;
  const int cblk = blockIdx.x * 128;
  const int wrow = (wid >> 1) * (BM / 2);
  const int wcol = (wid & 1) * 64;
  const int srow = lane >> 2;
  const int scol = (lane & 3) * 8;
  f32x4 acc[MFR][4] = {};

  for (int kk = 0; kk < K; kk += BK) {
#pragma unroll
    for (int j = 0; j < BM / 64; j++) {
      int seg = wid * (BM / 64) + j;
      const short* g = A + (size_t)(rblk + seg * 16 + srow) * K + kk + scol;
      __builtin_amdgcn_global_load_lds(GLB_PTR(g), LDS_PTR(&As[seg * 512]), 16, 0, 0);
    }
#pragma unroll
    for (int j = 0; j < 2; j++) {
      int seg = wid * 2 + j;
      const short* g = W + (size_t)(cblk + seg * 16 + srow) * K + kk + scol;
      __builtin_amdgcn_global_load_lds(GLB_PTR(g), LDS_PTR(&Bs[seg * 512]), 16, 0, 0);
    }
    __syncthreads();
    s16x8 af[MFR], bfr[4];
#pragma unroll
    for (int m = 0; m < MFR; m++)
      af[m] = *reinterpret_cast<const s16x8*>(&As[(wrow + m * 16 + lr) * BK + lg * 8]);
#pragma unroll
    for (int n = 0; n < 4; n++)
      bfr[n] = *reinterpret_cast<const s16x8*>(&Bs[(wcol + n * 16 + lr) * BK + lg * 8]);
#pragma unroll
    for (int m = 0; m < MFR; m++)
#pragma unroll
      for (int n = 0; n < 4; n++)
        acc[m][n] = __builtin_amdgcn_mfma_f32_16x16x32_bf16(af[m], bfr[n], acc[m][n], 0, 0, 0);
    __syncthreads();
  }
#pragma unroll
  for (int m = 0; m < MFR; m++)
#pragma unroll
    for (int n = 0; n < 4; n++)
#pragma unroll
      for (int r = 0; r < 4; r++) {
        int row = rblk + wrow + m * 16 + lg * 4 + r;
        int col = cblk + wcol + n * 16 + lr;
        float val = acc[m][n][r];
        if constexpr (BF16OUT) ((short*)Cv)[(size_t)row * N + col] = f2bf(val);
        else                   ((float*)Cv)[(size_t)row * N + col] = val;
      }
}

// proj (bf16, [B][T][3][H][D]) -> RoPE -> Qb/Kb ([B][H][T][D]) and Vt ([B][H][D][T])
__global__ __launch_bounds__(256) void rope_v2(const short* __restrict__ proj,
                                               short* __restrict__ Qb,
                                               short* __restrict__ Kb,
                                               short* __restrict__ Vt) {
  int tid = threadIdx.x;
  int t0 = blockIdx.x * 64;
  int bh = blockIdx.y;
  int b = bh >> 4, h = bh & 15;
  __shared__ short vtile[64 * 66];
  int i = tid & 31;
  int trow = tid >> 5;
  float freq = __expf(-(float)i * 0.2878231366f);  // ln(10000)/32
#pragma unroll
  for (int it = 0; it < 8; ++it) {
    int tl = it * 8 + trow;
    int t = t0 + tl;
    int pbase = (b * TT + t) * 3 * EMB + h * HD + 2 * i;
    unsigned q01 = *reinterpret_cast<const unsigned*>(proj + pbase);
    unsigned k01 = *reinterpret_cast<const unsigned*>(proj + pbase + EMB);
    unsigned v01 = *reinterpret_cast<const unsigned*>(proj + pbase + 2 * EMB);
    float qa = bf2f((unsigned short)(q01 & 0xffff)), qb_ = bf2f((unsigned short)(q01 >> 16));
    float ka = bf2f((unsigned short)(k01 & 0xffff)), kb_ = bf2f((unsigned short)(k01 >> 16));
    float ang = (float)t * freq;
    float s, c;
    sincosf(ang, &s, &c);
    int obase = (bh * TT + t) * HD + 2 * i;
    unsigned qo = ((unsigned)(unsigned short)f2bf(qa * s + qb_ * c) << 16) |
                  (unsigned short)f2bf(qa * c - qb_ * s);
    unsigned ko = ((unsigned)(unsigned short)f2bf(ka * s + kb_ * c) << 16) |
                  (unsigned short)f2bf(ka * c - kb_ * s);
    *reinterpret_cast<unsigned*>(Qb + obase) = qo;
    *reinterpret_cast<unsigned*>(Kb + obase) = ko;
    *reinterpret_cast<unsigned*>(&vtile[tl * 66 + 2 * i]) = v01;
  }
  __syncthreads();
  int d = tid >> 2, toff = (tid & 3) * 16;
  s16x8 o0, o1;
#pragma unroll
  for (int j = 0; j < 8; ++j) {
    o0[j] = vtile[(toff + j) * 66 + d];
    o1[j] = vtile[(toff + 8 + j) * 66 + d];
  }
  size_t vb = (size_t)(bh * HD + d) * TT + t0 + toff;
  *reinterpret_cast<s16x8*>(Vt + vb) = o0;
  *reinterpret_cast<s16x8*>(Vt + vb + 8) = o1;
}

// 4-wave blocks: 64 q-rows/block, K/V tiles staged once per block into
// swizzled LDS. XCD-chunked block mapping: 8 XCDs x 4 bh x 32 t-blocks.
__global__ __launch_bounds__(256) void attn_v3(const short* __restrict__ Qb,
                                               const short* __restrict__ Kb,
                                               const short* __restrict__ Vt,
                                               short* __restrict__ Xout) {
  const float NEG = -3.0e38f;
  int tid = threadIdx.x;
  int lane = tid & 63;
  int w = tid >> 6;
  int lr = lane & 15, lg = lane >> 4;
  int id = blockIdx.x;
  int xcd = id & 7;
  int sub = id >> 3;
  int bh = xcd * 4 + (sub >> 5);
  int tblk = (sub & 31) * 64;
  int t0 = tblk + w * 16;
  int b = bh >> 4, h = bh & 15;
  const short* Qp = Qb + bh * TT * HD;
  const char* Kp = (const char*)(Kb + bh * TT * HD);
  const char* Vtp = (const char*)(Vt + bh * HD * TT);
  __shared__ __align__(16) short Ks[32 * 64];
  __shared__ __align__(16) short Vs[64 * 32];
  __shared__ __align__(16) short p_lds[4][16][40];
  s16x8 qf[2];
#pragma unroll
  for (int d2 = 0; d2 < 2; d2++)
    qf[d2] = *reinterpret_cast<const s16x8*>(Qp + (t0 + lr) * HD + d2 * 32 + lg * 8);
  f32x4 of[4] = {};
  float m_run[4], l_run[4];
#pragma unroll
  for (int r = 0; r < 4; r++) { m_run[r] = NEG; l_run[r] = 0.0f; }
  int lo = tblk - (CTX - 1); if (lo < 0) lo = 0;
  int kt_lo = lo & ~31;
  int kt_hi = (tblk + 63) & ~31;
  int krow = w * 8 + (lane >> 3);
  int kcb  = ((lane & 7) * 16) ^ ((krow & 7) << 4);
  int vd   = w * 16 + (lane >> 2);
  int vcb  = ((lane & 3) * 16) ^ (((vd >> 1) & 3) << 4);
  char* ksdst = (char*)Ks + w * 1024 + lane * 16;
  char* vsdst = (char*)Vs + w * 1024 + lane * 16;
  for (int kt = kt_lo; kt <= kt_hi; kt += 32) {
    __builtin_amdgcn_global_load_lds(GLB_PTR(Kp + (kt + krow) * 128 + kcb),
                                     LDS_PTR(ksdst), 16, 0, 0);
    __builtin_amdgcn_global_load_lds(GLB_PTR(Vtp + vd * (TT * 2) + kt * 2 + vcb),
                                     LDS_PTR(vsdst), 16, 0, 0);
    __syncthreads();
    if (kt <= t0 + 15 && kt + 31 >= t0 - (CTX - 1)) {
      f32x4 s2[2];
#pragma unroll
      for (int hh = 0; hh < 2; hh++) {
        int row = hh * 16 + lr;
        f32x4 sa = {};
#pragma unroll
        for (int d2 = 0; d2 < 2; d2++) {
          int cb = (d2 * 64 + lg * 16) ^ ((row & 7) << 4);
          s16x8 kf = *reinterpret_cast<const s16x8*>((const char*)Ks + row * 128 + cb);
          sa = __builtin_amdgcn_mfma_f32_16x16x32_bf16(qf[d2], kf, sa, 0, 0, 0);
        }
        s2[hh] = sa;
      }
#pragma unroll
      for (int r = 0; r < 4; r++) {
        int row = t0 + lg * 4 + r;
        float sv[2]; bool vdm[2];
#pragma unroll
        for (int hh = 0; hh < 2; hh++) {
          int col = kt + hh * 16 + lr;
          int dl = row - col;
          vdm[hh] = (dl >= 0) && (dl < CTX);
          sv[hh] = vdm[hh] ? s2[hh][r] * 0.125f : NEG;
        }
        float mx = fmaxf(sv[0], sv[1]);
#pragma unroll
        for (int off = 1; off < 16; off <<= 1) mx = fmaxf(mx, __shfl_xor(mx, off, 16));
        float mnew = fmaxf(m_run[r], mx);
        float corr = __expf(m_run[r] - mnew);
        float psum = 0.0f;
#pragma unroll
        for (int hh = 0; hh < 2; hh++) {
          float pv = vdm[hh] ? __expf(sv[hh] - mnew) : 0.0f;
          p_lds[w][lg * 4 + r][hh * 16 + lr] = f2bf(pv);
          psum += pv;
        }
#pragma unroll
        for (int off = 1; off < 16; off <<= 1) psum += __shfl_xor(psum, off, 16);
        l_run[r] = l_run[r] * corr + psum;
        m_run[r] = mnew;
#pragma unroll
        for (int n = 0; n < 4; n++) of[n][r] *= corr;
      }
      s16x8 pa = *reinterpret_cast<const s16x8*>(&p_lds[w][lr][lg * 8]);
#pragma unroll
      for (int n = 0; n < 4; n++) {
        int d = n * 16 + lr;
        int cb = (lg * 16) ^ (((d >> 1) & 3) << 4);
        s16x8 vf = *reinterpret_cast<const s16x8*>((const char*)Vs + d * 64 + cb);
        of[n] = __builtin_amdgcn_mfma_f32_16x16x32_bf16(pa, vf, of[n], 0, 0, 0);
      }
    }
    __syncthreads();
  }
#pragma unroll
  for (int r = 0; r < 4; r++) {
    float inv = 1.0f / l_run[r];
    int row = t0 + lg * 4 + r;
#pragma unroll
    for (int n = 0; n < 4; n++)
      Xout[(b * TT + row) * EMB + h * HD + n * 16 + lr] = f2bf(of[n][r] * inv);
  }
}

extern "C" void kernel_launch(void* const* d_in, const int* in_sizes, int n_in,
                              void* d_out, int out_size, void* d_ws, size_t ws_size,
                              hipStream_t stream) {
  const float* query = (const float*)d_in[0];
  const float* w_in  = (const float*)d_in[1];
  const float* w_out = (const float*)d_in[2];
  char* ws = (char*)d_ws;
  short* qbf   = (short*)(ws + 0);          //  8388608  query bf16 [4096][1024]
  short* wibf  = (short*)(ws + 8388608);    //  6291456  in_proj bf16 [3072][1024]
  short* wobf  = (short*)(ws + 14680064);   //  2097152  out_proj bf16 [1024][1024]
  short* proj  = (short*)(ws + 16777216);   // 25165824  qkv proj bf16 [4096][3072]
  short* attnx = (short*)(ws + 16777216);   // alias: proj dead after rope
  short* Qb    = (short*)(ws + 41943040);   //  8388608  [B][H][T][D]
  short* Kb    = (short*)(ws + 50331648);   //  8388608  [B][H][T][D]
  short* Vt    = (short*)(ws + 58720256);   //  8388608  [B][H][D][T]

  cvt_all<<<8192, 256, 0, stream>>>(query, w_in, w_out, qbf, wibf, wobf);
  gemm_256<true><<<192, 512, 0, stream>>>(qbf, wibf, (void*)proj, 3072, 1024);
  rope_v2<<<dim3(32, 32), 256, 0, stream>>>(proj, Qb, Kb, Vt);
  attn_v3<<<1024, 256, 0, stream>>>(Qb, Kb, Vt, attnx);
  gemm_lds<64, false><<<dim3(8, 64), 256, 0, stream>>>(attnx, wobf, d_out, 1024, 1024);
}

// Round 9
// 109.767 us; speedup vs baseline: 1.0703x; 1.0038x over previous
//
#include <hip/hip_runtime.h>

#define TT 2048
#define EMB 1024
#define NH 16
#define HD 64
#define CTX 250

typedef __attribute__((ext_vector_type(4))) float f32x4;
typedef __attribute__((ext_vector_type(8))) short s16x8;
typedef __attribute__((ext_vector_type(4))) short s16x4;

#define LDS_PTR(p) ((__attribute__((address_space(3))) void*)(p))
#define GLB_PTR(p) ((const __attribute__((address_space(1))) void*)(p))

__device__ __forceinline__ short f2bf(float f) {
  union { float f; unsigned u; } v; v.f = f;
  unsigned r = v.u + 0x7fffu + ((v.u >> 16) & 1u);
  return (short)(r >> 16);
}
__device__ __forceinline__ float bf2f(unsigned short u) {
  union { unsigned u; float f; } v; v.u = ((unsigned)u) << 16;
  return v.f;
}

// one kernel converts all three f32 inputs to bf16
// segments (float4 units): q = 1048576, wi = 786432, wo = 262144; total 2097152
__global__ void cvt_all(const float* __restrict__ q, const float* __restrict__ wi,
                        const float* __restrict__ wo, short* __restrict__ qo,
                        short* __restrict__ wio, short* __restrict__ woo) {
  int i = blockIdx.x * blockDim.x + threadIdx.x;
  const float* src; short* dst; int off;
  if (i < 1048576)      { src = q;  dst = qo;  off = i; }
  else if (i < 1835008) { src = wi; dst = wio; off = i - 1048576; }
  else                  { src = wo; dst = woo; off = i - 1835008; }
  float4 v = reinterpret_cast<const float4*>(src)[off];
  s16x4 o; o[0] = f2bf(v.x); o[1] = f2bf(v.y); o[2] = f2bf(v.z); o[3] = f2bf(v.w);
  *reinterpret_cast<s16x4*>(dst + off * 4) = o;
}

// ---------------------------------------------------------------------------
// 8-phase 256x256 GEMM (m201-style), BK=32, 8 waves (2M x 4N), RING-4 LDS.
// Per K-tile: 2 phases x 16 MFMA, each phase:
//   {ds_read frags || issue 2 stage ops for tile t+3} -> barrier ->
//   setprio(1) 16 MFMA setprio(0) -> barrier
// vmcnt counted (8 steady; 8->4->0 epilogue ladder), never drained mid-loop.
// LDS [rows][32] bf16 rows of 64B: fragment reads are bank-BALANCED
// (row stride = 16 banks), no swizzle needed.
// Ring-4 WAR: stage target buf[(t+3)&3]=buf[(t-1)&3]; tile t-1's reads are
// physically done before its phase-1 second barrier (lgkm wait precedes it),
// and tile t's stage ops issue after that barrier.
// ---------------------------------------------------------------------------
template<bool BF16OUT>
__global__ __launch_bounds__(512, 2) void gemm_8p(const short* __restrict__ A,
                                                  const short* __restrict__ W,
                                                  void* __restrict__ Cv, int N, int K) {
  __shared__ __align__(16) short lds[4][2][8192];  // [ring][A/B][256 rows x 32 k]
  const int tid = threadIdx.x, lane = tid & 63, wid = tid >> 6;
  const int lr = lane & 15, lg = lane >> 4;
  const int wm = wid >> 2, wn = wid & 3;           // wave grid 2M x 4N
  const int nwg = gridDim.x, cpx = nwg >> 3;       // XCD-chunked swizzle (192%8==0)
  const int swz = (blockIdx.x & 7) * cpx + (blockIdx.x >> 3);
  const int nbx = N >> 8;
  const int rblk = (swz / nbx) << 8, cblk = (swz % nbx) << 8;
  const short* Ag = A + (size_t)rblk * K;
  const short* Wg = W + (size_t)cblk * K;
  const int srow = lane >> 2, scol = (lane & 3) * 8;  // staging: 16 rows x 64B
  const int sseg0 = wid * 2, sseg1 = wid * 2 + 1;     // 16 segs per matrix / 8 waves
  f32x4 acc[8][4] = {};
  const int NT = K >> 5;  // 32 K-tiles

#define ST_OP(t, rg, ab, seg)                                                        \
  __builtin_amdgcn_global_load_lds(                                                  \
      GLB_PTR(((ab) ? Wg : Ag) + (size_t)((seg) * 16 + srow) * K + ((t) << 5) + scol), \
      LDS_PTR(&lds[rg][ab][(seg) * 512]), 16, 0, 0)

  // prologue: stage tiles 0,1,2 (12 ops/thread-wave); tile0 sealed by vmcnt(8)
  ST_OP(0, 0, 0, sseg0); ST_OP(0, 0, 1, sseg0); ST_OP(0, 0, 0, sseg1); ST_OP(0, 0, 1, sseg1);
  ST_OP(1, 1, 0, sseg0); ST_OP(1, 1, 1, sseg0); ST_OP(1, 1, 0, sseg1); ST_OP(1, 1, 1, sseg1);
  ST_OP(2, 2, 0, sseg0); ST_OP(2, 2, 1, sseg0); ST_OP(2, 2, 0, sseg1); ST_OP(2, 2, 1, sseg1);
  asm volatile("s_waitcnt vmcnt(8)" ::: "memory");
  __builtin_amdgcn_s_barrier();

  for (int t = 0; t < NT; ++t) {
    const int rg = t & 3;
    const int rgs = (t + 3) & 3;
    const bool st = (t + 3) < NT;
    const short* la = lds[rg][0];
    const short* lb = lds[rg][1];
    s16x8 af[4], bfv[4];
    // ---------------- phase 0: m-half 0 ----------------
#pragma unroll
    for (int m = 0; m < 4; m++)
      af[m] = *reinterpret_cast<const s16x8*>(&la[(wm * 128 + m * 16 + lr) * 32 + lg * 8]);
#pragma unroll
    for (int n = 0; n < 4; n++)
      bfv[n] = *reinterpret_cast<const s16x8*>(&lb[(wn * 64 + n * 16 + lr) * 32 + lg * 8]);
    if (st) { ST_OP(t + 3, rgs, 0, sseg0); ST_OP(t + 3, rgs, 1, sseg0); }
    __builtin_amdgcn_s_barrier();
    __builtin_amdgcn_s_setprio(1);
#pragma unroll
    for (int m = 0; m < 4; m++)
#pragma unroll
      for (int n = 0; n < 4; n++)
        acc[m][n] = __builtin_amdgcn_mfma_f32_16x16x32_bf16(af[m], bfv[n], acc[m][n], 0, 0, 0);
    __builtin_amdgcn_s_setprio(0);
    __builtin_amdgcn_s_barrier();
    // ---------------- phase 1: m-half 1 ----------------
#pragma unroll
    for (int m = 0; m < 4; m++)
      af[m] = *reinterpret_cast<const s16x8*>(&la[(wm * 128 + 64 + m * 16 + lr) * 32 + lg * 8]);
    if (st) { ST_OP(t + 3, rgs, 0, sseg1); ST_OP(t + 3, rgs, 1, sseg1); }
    if (t + 3 < NT)      asm volatile("s_waitcnt vmcnt(8)" ::: "memory");
    else if (t + 2 < NT) asm volatile("s_waitcnt vmcnt(4)" ::: "memory");
    else                 asm volatile("s_waitcnt vmcnt(0)" ::: "memory");
    __builtin_amdgcn_s_barrier();     // tile t+1 staged+visible to ALL waves
    __builtin_amdgcn_s_setprio(1);
#pragma unroll
    for (int m = 0; m < 4; m++)
#pragma unroll
      for (int n = 0; n < 4; n++)
        acc[4 + m][n] = __builtin_amdgcn_mfma_f32_16x16x32_bf16(af[m], bfv[n], acc[4 + m][n], 0, 0, 0);
    __builtin_amdgcn_s_setprio(0);
    __builtin_amdgcn_s_barrier();     // seals this tile's reads before its buf is re-staged
  }
#undef ST_OP

#pragma unroll
  for (int mf = 0; mf < 8; mf++)
#pragma unroll
    for (int nf = 0; nf < 4; nf++)
#pragma unroll
      for (int r = 0; r < 4; r++) {
        int row = rblk + wm * 128 + mf * 16 + lg * 4 + r;
        int col = cblk + wn * 64 + nf * 16 + lr;
        float val = acc[mf][nf][r];
        if constexpr (BF16OUT) ((short*)Cv)[(size_t)row * N + col] = f2bf(val);
        else                   ((float*)Cv)[(size_t)row * N + col] = val;
      }
}

// m97-structure GEMM kept for the out-projection (N=1024 -> needs small tiles)
template<int BM, bool BF16OUT>
__global__ __launch_bounds__(256) void gemm_lds(const short* __restrict__ A,
                                                const short* __restrict__ W,
                                                void* __restrict__ Cv, int N, int K) {
  constexpr int BK = 32;
  constexpr int MFR = BM / 32;
  __shared__ __align__(16) short As[BM * BK];
  __shared__ __align__(16) short Bs[128 * BK];
  const int lane = threadIdx.x & 63;
  const int wid  = threadIdx.x >> 6;
  const int lr = lane & 15, lg = lane >> 4;
  const int rblk = blockIdx.y * BM;
  const int cblk = blockIdx.x * 128;
  const int wrow = (wid >> 1) * (BM / 2);
  const int wcol = (wid & 1) * 64;
  const int srow = lane >> 2;
  const int scol = (lane & 3) * 8;
  f32x4 acc[MFR][4] = {};

  for (int kk = 0; kk < K; kk += BK) {
#pragma unroll
    for (int j = 0; j < BM / 64; j++) {
      int seg = wid * (BM / 64) + j;
      const short* g = A + (size_t)(rblk + seg * 16 + srow) * K + kk + scol;
      __builtin_amdgcn_global_load_lds(GLB_PTR(g), LDS_PTR(&As[seg * 512]), 16, 0, 0);
    }
#pragma unroll
    for (int j = 0; j < 2; j++) {
      int seg = wid * 2 + j;
      const short* g = W + (size_t)(cblk + seg * 16 + srow) * K + kk + scol;
      __builtin_amdgcn_global_load_lds(GLB_PTR(g), LDS_PTR(&Bs[seg * 512]), 16, 0, 0);
    }
    __syncthreads();
    s16x8 af[MFR], bfr[4];
#pragma unroll
    for (int m = 0; m < MFR; m++)
      af[m] = *reinterpret_cast<const s16x8*>(&As[(wrow + m * 16 + lr) * BK + lg * 8]);
#pragma unroll
    for (int n = 0; n < 4; n++)
      bfr[n] = *reinterpret_cast<const s16x8*>(&Bs[(wcol + n * 16 + lr) * BK + lg * 8]);
#pragma unroll
    for (int m = 0; m < MFR; m++)
#pragma unroll
      for (int n = 0; n < 4; n++)
        acc[m][n] = __builtin_amdgcn_mfma_f32_16x16x32_bf16(af[m], bfr[n], acc[m][n], 0, 0, 0);
    __syncthreads();
  }
#pragma unroll
  for (int m = 0; m < MFR; m++)
#pragma unroll
    for (int n = 0; n < 4; n++)
#pragma unroll
      for (int r = 0; r < 4; r++) {
        int row = rblk + wrow + m * 16 + lg * 4 + r;
        int col = cblk + wcol + n * 16 + lr;
        float val = acc[m][n][r];
        if constexpr (BF16OUT) ((short*)Cv)[(size_t)row * N + col] = f2bf(val);
        else                   ((float*)Cv)[(size_t)row * N + col] = val;
      }
}

// proj (bf16, [B][T][3][H][D]) -> RoPE -> Qb/Kb ([B][H][T][D]) and Vt ([B][H][D][T])
__global__ __launch_bounds__(256) void rope_v2(const short* __restrict__ proj,
                                               short* __restrict__ Qb,
                                               short* __restrict__ Kb,
                                               short* __restrict__ Vt) {
  int tid = threadIdx.x;
  int t0 = blockIdx.x * 64;
  int bh = blockIdx.y;
  int b = bh >> 4, h = bh & 15;
  __shared__ short vtile[64 * 66];
  int i = tid & 31;
  int trow = tid >> 5;
  float freq = __expf(-(float)i * 0.2878231366f);  // ln(10000)/32
#pragma unroll
  for (int it = 0; it < 8; ++it) {
    int tl = it * 8 + trow;
    int t = t0 + tl;
    int pbase = (b * TT + t) * 3 * EMB + h * HD + 2 * i;
    unsigned q01 = *reinterpret_cast<const unsigned*>(proj + pbase);
    unsigned k01 = *reinterpret_cast<const unsigned*>(proj + pbase + EMB);
    unsigned v01 = *reinterpret_cast<const unsigned*>(proj + pbase + 2 * EMB);
    float qa = bf2f((unsigned short)(q01 & 0xffff)), qb_ = bf2f((unsigned short)(q01 >> 16));
    float ka = bf2f((unsigned short)(k01 & 0xffff)), kb_ = bf2f((unsigned short)(k01 >> 16));
    float ang = (float)t * freq;
    float s, c;
    sincosf(ang, &s, &c);
    int obase = (bh * TT + t) * HD + 2 * i;
    unsigned qo = ((unsigned)(unsigned short)f2bf(qa * s + qb_ * c) << 16) |
                  (unsigned short)f2bf(qa * c - qb_ * s);
    unsigned ko = ((unsigned)(unsigned short)f2bf(ka * s + kb_ * c) << 16) |
                  (unsigned short)f2bf(ka * c - kb_ * s);
    *reinterpret_cast<unsigned*>(Qb + obase) = qo;
    *reinterpret_cast<unsigned*>(Kb + obase) = ko;
    *reinterpret_cast<unsigned*>(&vtile[tl * 66 + 2 * i]) = v01;
  }
  __syncthreads();
  int d = tid >> 2, toff = (tid & 3) * 16;
  s16x8 o0, o1;
#pragma unroll
  for (int j = 0; j < 8; ++j) {
    o0[j] = vtile[(toff + j) * 66 + d];
    o1[j] = vtile[(toff + 8 + j) * 66 + d];
  }
  size_t vb = (size_t)(bh * HD + d) * TT + t0 + toff;
  *reinterpret_cast<s16x8*>(Vt + vb) = o0;
  *reinterpret_cast<s16x8*>(Vt + vb + 8) = o1;
}

// 4-wave blocks: 64 q-rows/block, K/V tiles staged once per block into
// swizzled LDS. XCD-chunked block mapping: 8 XCDs x 4 bh x 32 t-blocks.
__global__ __launch_bounds__(256) void attn_v3(const short* __restrict__ Qb,
                                               const short* __restrict__ Kb,
                                               const short* __restrict__ Vt,
                                               short* __restrict__ Xout) {
  const float NEG = -3.0e38f;
  int tid = threadIdx.x;
  int lane = tid & 63;
  int w = tid >> 6;
  int lr = lane & 15, lg = lane >> 4;
  int id = blockIdx.x;
  int xcd = id & 7;
  int sub = id >> 3;
  int bh = xcd * 4 + (sub >> 5);
  int tblk = (sub & 31) * 64;
  int t0 = tblk + w * 16;
  int b = bh >> 4, h = bh & 15;
  const short* Qp = Qb + bh * TT * HD;
  const char* Kp = (const char*)(Kb + bh * TT * HD);
  const char* Vtp = (const char*)(Vt + bh * HD * TT);
  __shared__ __align__(16) short Ks[32 * 64];
  __shared__ __align__(16) short Vs[64 * 32];
  __shared__ __align__(16) short p_lds[4][16][40];
  s16x8 qf[2];
#pragma unroll
  for (int d2 = 0; d2 < 2; d2++)
    qf[d2] = *reinterpret_cast<const s16x8*>(Qp + (t0 + lr) * HD + d2 * 32 + lg * 8);
  f32x4 of[4] = {};
  float m_run[4], l_run[4];
#pragma unroll
  for (int r = 0; r < 4; r++) { m_run[r] = NEG; l_run[r] = 0.0f; }
  int lo = tblk - (CTX - 1); if (lo < 0) lo = 0;
  int kt_lo = lo & ~31;
  int kt_hi = (tblk + 63) & ~31;
  int krow = w * 8 + (lane >> 3);
  int kcb  = ((lane & 7) * 16) ^ ((krow & 7) << 4);
  int vd   = w * 16 + (lane >> 2);
  int vcb  = ((lane & 3) * 16) ^ (((vd >> 1) & 3) << 4);
  char* ksdst = (char*)Ks + w * 1024 + lane * 16;
  char* vsdst = (char*)Vs + w * 1024 + lane * 16;
  for (int kt = kt_lo; kt <= kt_hi; kt += 32) {
    __builtin_amdgcn_global_load_lds(GLB_PTR(Kp + (kt + krow) * 128 + kcb),
                                     LDS_PTR(ksdst), 16, 0, 0);
    __builtin_amdgcn_global_load_lds(GLB_PTR(Vtp + vd * (TT * 2) + kt * 2 + vcb),
                                     LDS_PTR(vsdst), 16, 0, 0);
    __syncthreads();
    if (kt <= t0 + 15 && kt + 31 >= t0 - (CTX - 1)) {
      f32x4 s2[2];
#pragma unroll
      for (int hh = 0; hh < 2; hh++) {
        int row = hh * 16 + lr;
        f32x4 sa = {};
#pragma unroll
        for (int d2 = 0; d2 < 2; d2++) {
          int cb = (d2 * 64 + lg * 16) ^ ((row & 7) << 4);
          s16x8 kf = *reinterpret_cast<const s16x8*>((const char*)Ks + row * 128 + cb);
          sa = __builtin_amdgcn_mfma_f32_16x16x32_bf16(qf[d2], kf, sa, 0, 0, 0);
        }
        s2[hh] = sa;
      }
#pragma unroll
      for (int r = 0; r < 4; r++) {
        int row = t0 + lg * 4 + r;
        float sv[2]; bool vdm[2];
#pragma unroll
        for (int hh = 0; hh < 2; hh++) {
          int col = kt + hh * 16 + lr;
          int dl = row - col;
          vdm[hh] = (dl >= 0) && (dl < CTX);
          sv[hh] = vdm[hh] ? s2[hh][r] * 0.125f : NEG;
        }
        float mx = fmaxf(sv[0], sv[1]);
#pragma unroll
        for (int off = 1; off < 16; off <<= 1) mx = fmaxf(mx, __shfl_xor(mx, off, 16));
        float mnew = fmaxf(m_run[r], mx);
        float corr = __expf(m_run[r] - mnew);
        float psum = 0.0f;
#pragma unroll
        for (int hh = 0; hh < 2; hh++) {
          float pv = vdm[hh] ? __expf(sv[hh] - mnew) : 0.0f;
          p_lds[w][lg * 4 + r][hh * 16 + lr] = f2bf(pv);
          psum += pv;
        }
#pragma unroll
        for (int off = 1; off < 16; off <<= 1) psum += __shfl_xor(psum, off, 16);
        l_run[r] = l_run[r] * corr + psum;
        m_run[r] = mnew;
#pragma unroll
        for (int n = 0; n < 4; n++) of[n][r] *= corr;
      }
      s16x8 pa = *reinterpret_cast<const s16x8*>(&p_lds[w][lr][lg * 8]);
#pragma unroll
      for (int n = 0; n < 4; n++) {
        int d = n * 16 + lr;
        int cb = (lg * 16) ^ (((d >> 1) & 3) << 4);
        s16x8 vf = *reinterpret_cast<const s16x8*>((const char*)Vs + d * 64 + cb);
        of[n] = __builtin_amdgcn_mfma_f32_16x16x32_bf16(pa, vf, of[n], 0, 0, 0);
      }
    }
    __syncthreads();
  }
#pragma unroll
  for (int r = 0; r < 4; r++) {
    float inv = 1.0f / l_run[r];
    int row = t0 + lg * 4 + r;
#pragma unroll
    for (int n = 0; n < 4; n++)
      Xout[(b * TT + row) * EMB + h * HD + n * 16 + lr] = f2bf(of[n][r] * inv);
  }
}

extern "C" void kernel_launch(void* const* d_in, const int* in_sizes, int n_in,
                              void* d_out, int out_size, void* d_ws, size_t ws_size,
                              hipStream_t stream) {
  const float* query = (const float*)d_in[0];
  const float* w_in  = (const float*)d_in[1];
  const float* w_out = (const float*)d_in[2];
  char* ws = (char*)d_ws;
  short* qbf   = (short*)(ws + 0);          //  8388608  query bf16 [4096][1024]
  short* wibf  = (short*)(ws + 8388608);    //  6291456  in_proj bf16 [3072][1024]
  short* wobf  = (short*)(ws + 14680064);   //  2097152  out_proj bf16 [1024][1024]
  short* proj  = (short*)(ws + 16777216);   // 25165824  qkv proj bf16 [4096][3072]
  short* attnx = (short*)(ws + 16777216);   // alias: proj dead after rope
  short* Qb    = (short*)(ws + 41943040);   //  8388608  [B][H][T][D]
  short* Kb    = (short*)(ws + 50331648);   //  8388608  [B][H][T][D]
  short* Vt    = (short*)(ws + 58720256);   //  8388608  [B][H][D][T]

  cvt_all<<<8192, 256, 0, stream>>>(query, w_in, w_out, qbf, wibf, wobf);
  gemm_8p<true><<<192, 512, 0, stream>>>(qbf, wibf, (void*)proj, 3072, 1024);
  rope_v2<<<dim3(32, 32), 256, 0, stream>>>(proj, Qb, Kb, Vt);
  attn_v3<<<1024, 256, 0, stream>>>(Qb, Kb, Vt, attnx);
  gemm_lds<64, false><<<dim3(8, 64), 256, 0, stream>>>(attnx, wobf, d_out, 1024, 1024);
}